// Round 3
// baseline (394.696 us; speedup 1.0000x reference)
//
#include <hip/hip_runtime.h>

typedef unsigned int uint_t;

// Problem: B=8, C=256, H=W=64, K=3, pad=1, stride=1
// Inputs: float32 [8,256,64,64]; Output: float32, 8*256*4096*9 = 75,497,472.
// out[b,c,l2,j2] = kflat_bc[l2*9+j2] * qflat_bc[l2*9+4], where flat index
// p decodes in unfold layout as p = j*4096 + l, j=kh*3+kw, l=h*64+w,
// value = plane[h+kh-1, w+kw-1] (0 if padding).
#define HW        4096        // 64*64
#define CHUNKS_PER_BC 4608    // 9*4096/8
#define NBLOCKS   36864       // (2048*4608)/256

// qcenter[l2] = qflat_bc[l2*9 + 4]; decompose idx -> (j4, l4) -> padded tap.
static __device__ __forceinline__ float qload(const float* __restrict__ qplane, int l2) {
    int idx = l2 * 9 + 4;
    int j4  = idx >> 12;
    int l4  = idx & 4095;
    int h4  = l4 >> 6;
    int w4  = l4 & 63;
    int jd  = (j4 * 11) >> 5;          // j4 / 3 for j4 in [0,8]
    int hh  = h4 + jd - 1;
    int ww  = w4 + (j4 - jd * 3) - 1;
    if ((unsigned)hh < 64u && (unsigned)ww < 64u)
        return qplane[(hh << 6) + ww];
    return 0.0f;
}

__global__ __launch_bounds__(256) void appcomp_kernel(
    const float* __restrict__ key,
    const float* __restrict__ query,
    float* __restrict__ out)
{
    int g  = blockIdx.x * 256 + threadIdx.x;   // chunk id, exact grid
    int bc = g / CHUNKS_PER_BC;
    int t  = g - bc * CHUNKS_PER_BC;
    int r  = t << 3;                 // base p within (b,c), [0, 36864)
    int j  = r >> 12;                // patch tap index 0..8 (wave-uniform)
    int l  = r & 4095;
    int h  = l >> 6;
    int w0 = l & 63;                 // multiple of 8

    int jd3 = (j * 11) >> 5;         // j/3
    int dh  = jd3 - 1;
    int dw  = j - jd3 * 3 - 1;       // wave-uniform
    int hh  = h + dh;

    const float* kplane = key + bc * HW;

    float kf[8];
    if ((unsigned)hh < 64u) {
        const float* rowp = kplane + (hh << 6);
        float4 a = *(const float4*)(rowp + w0);       // 16B aligned (w0 % 8 == 0)
        float4 b = *(const float4*)(rowp + w0 + 4);
        float e[8] = {a.x, a.y, a.z, a.w, b.x, b.y, b.z, b.w};
        if (dw == 0) {
            #pragma unroll
            for (int i = 0; i < 8; i++) kf[i] = e[i];
        } else if (dw < 0) {
            kf[0] = (w0 > 0) ? rowp[w0 - 1] : 0.0f;
            #pragma unroll
            for (int i = 1; i < 8; i++) kf[i] = e[i - 1];
        } else {
            #pragma unroll
            for (int i = 0; i < 7; i++) kf[i] = e[i + 1];
            kf[7] = (w0 < 56) ? rowp[w0 + 8] : 0.0f;
        }
    } else {
        #pragma unroll
        for (int i = 0; i < 8; i++) kf[i] = 0.0f;
    }

    // query factors: 8 consecutive p span at most two l2 = p/9 values
    int l2a   = r / 9;
    int m9    = r - l2a * 9;
    int split = 9 - m9;              // elements [0, split) use qa, rest qb
    const float* qplane = query + bc * HW;
    float qa = qload(qplane, l2a);
    float qb = (split < 8) ? qload(qplane, l2a + 1) : 0.0f;

    float f[8];
    #pragma unroll
    for (int i = 0; i < 8; i++) {
        float q = (i < split) ? qa : qb;
        f[i] = kf[i] * q;
    }

    float* op = out + (size_t)g * 8;
    *(float4*)(op)     = make_float4(f[0], f[1], f[2], f[3]);
    *(float4*)(op + 4) = make_float4(f[4], f[5], f[6], f[7]);
}

extern "C" void kernel_launch(void* const* d_in, const int* in_sizes, int n_in,
                              void* d_out, int out_size, void* d_ws, size_t ws_size,
                              hipStream_t stream) {
    const float* key   = (const float*)d_in[0];
    const float* query = (const float*)d_in[1];
    float* out = (float*)d_out;
    appcomp_kernel<<<NBLOCKS, 256, 0, stream>>>(key, query, out);
}

// Round 4
// 356.371 us; speedup vs baseline: 1.1075x; 1.1075x over previous
//
#include <hip/hip_runtime.h>

// Problem: B=8, C=256, H=W=64, K=3, pad=1, stride=1
// Inputs: float32 [8,256,64,64] (33.5 MB each); Output: float32, 75,497,472.
// out_flat[bc*36864 + p] = kflat_bc[p] * qflat_bc[(p/9)*9 + 4]
// where flat unfold index p = j*4096 + l, j=kh*3+kw, l=h*64+w,
// value = plane[h+kh-1, w+kw-1] (0 if padding).
//
// One block per bc plane: stage key+query plane (16 KB each) in LDS once,
// compute all 36864 outputs from LDS. 18 chunks of 8 outputs per thread.
#define HW 4096

// qcenter[l2] = qflat_bc[l2*9 + 4]; decompose idx -> (j4, l4) -> padded tap.
static __device__ __forceinline__ float qload_lds(const float* q_s, int l2) {
    int idx = l2 * 9 + 4;
    int j4  = idx >> 12;
    int l4  = idx & 4095;
    int h4  = l4 >> 6;
    int w4  = l4 & 63;
    int jd  = (j4 * 11) >> 5;          // j4 / 3 for j4 in [0,8]
    int hh  = h4 + jd - 1;
    int ww  = w4 + (j4 - jd * 3) - 1;
    if ((unsigned)hh < 64u && (unsigned)ww < 64u)
        return q_s[(hh << 6) + ww];
    return 0.0f;
}

__global__ __launch_bounds__(256) void appcomp_kernel(
    const float* __restrict__ key,
    const float* __restrict__ query,
    float* __restrict__ out)
{
    __shared__ float k_s[HW];
    __shared__ float q_s[HW];

    const int bc  = blockIdx.x;          // 2048 blocks, one per (b,c)
    const int tid = threadIdx.x;

    // Phase 1: stage both planes, fully coalesced float4.
    {
        const float4* kg = (const float4*)(key + bc * HW);
        const float4* qg = (const float4*)(query + bc * HW);
        float4* k4 = (float4*)k_s;
        float4* q4 = (float4*)q_s;
        #pragma unroll
        for (int i = 0; i < 4; i++) {
            int idx = i * 256 + tid;
            k4[idx] = kg[idx];
            q4[idx] = qg[idx];
        }
    }
    __syncthreads();

    // Phase 2: 18 chunks of 8 consecutive outputs per thread.
    float* oplane = out + (size_t)bc * 36864;
    for (int i = 0; i < 18; i++) {
        int t  = i * 256 + tid;
        int r  = t << 3;                 // base p, [0, 36864)
        int j  = r >> 12;                // tap index 0..8 (wave-uniform)
        int l  = r & 4095;
        int h  = l >> 6;
        int w0 = l & 63;                 // multiple of 8

        int jd3 = (j * 11) >> 5;         // j/3
        int dh  = jd3 - 1;
        int dw  = j - jd3 * 3 - 1;       // wave-uniform
        int hh  = h + dh;

        float kf[8];
        if ((unsigned)hh < 64u) {
            const float* rowp = k_s + (hh << 6);
            float4 a = *(const float4*)(rowp + w0);      // 16B-aligned LDS
            float4 b = *(const float4*)(rowp + w0 + 4);
            float e[8] = {a.x, a.y, a.z, a.w, b.x, b.y, b.z, b.w};
            if (dw == 0) {
                #pragma unroll
                for (int q = 0; q < 8; q++) kf[q] = e[q];
            } else if (dw < 0) {
                kf[0] = (w0 > 0) ? rowp[w0 - 1] : 0.0f;
                #pragma unroll
                for (int q = 1; q < 8; q++) kf[q] = e[q - 1];
            } else {
                #pragma unroll
                for (int q = 0; q < 7; q++) kf[q] = e[q + 1];
                kf[7] = (w0 < 56) ? rowp[w0 + 8] : 0.0f;
            }
        } else {
            #pragma unroll
            for (int q = 0; q < 8; q++) kf[q] = 0.0f;
        }

        // query factors: 8 consecutive p span at most two l2 = p/9 values
        int l2a   = r / 9;
        int m9    = r - l2a * 9;
        int split = 9 - m9;              // [0, split) use qa, rest qb
        float qa = qload_lds(q_s, l2a);
        float qb = (split < 8) ? qload_lds(q_s, l2a + 1) : 0.0f;

        float f[8];
        #pragma unroll
        for (int q = 0; q < 8; q++)
            f[q] = kf[q] * ((q < split) ? qa : qb);

        float* op = oplane + r;
        *(float4*)(op)     = make_float4(f[0], f[1], f[2], f[3]);
        *(float4*)(op + 4) = make_float4(f[4], f[5], f[6], f[7]);
    }
}

extern "C" void kernel_launch(void* const* d_in, const int* in_sizes, int n_in,
                              void* d_out, int out_size, void* d_ws, size_t ws_size,
                              hipStream_t stream) {
    const float* key   = (const float*)d_in[0];
    const float* query = (const float*)d_in[1];
    float* out = (float*)d_out;
    appcomp_kernel<<<2048, 256, 0, stream>>>(key, query, out);
}

// Round 5
// 353.656 us; speedup vs baseline: 1.1160x; 1.0077x over previous
//
#include <hip/hip_runtime.h>

// Problem: B=8, C=256, H=W=64, K=3, pad=1, stride=1
// Inputs: float32 [8,256,64,64] (33.5 MB each); Output: float32, 75,497,472.
// out_flat[bc*36864 + p] = kflat_bc[p] * qflat_bc[(p/9)*9 + 4]
// where flat unfold index p = j*4096 + l, j=kh*3+kw, l=h*64+w,
// value = plane[h+kh-1, w+kw-1] (0 if padding).
//
// One block per bc plane: stage key+query plane (16 KB each) in LDS once.
// chunk = 4 floats/thread so each global_store_dwordx4 is DENSE across the
// wave (64 lanes x 16 B = 1 KB contiguous) — the round-4 8-float chunks made
// every store instruction stride-32B (half-covered cache lines).
#define HW 4096

// qcenter[l2] = qflat_bc[l2*9 + 4]; decompose idx -> (j4, l4) -> padded tap.
static __device__ __forceinline__ float qload_lds(const float* q_s, int l2) {
    int idx = l2 * 9 + 4;
    int j4  = idx >> 12;
    int l4  = idx & 4095;
    int h4  = l4 >> 6;
    int w4  = l4 & 63;
    int jd  = (j4 * 11) >> 5;          // j4 / 3 for j4 in [0,8]
    int hh  = h4 + jd - 1;
    int ww  = w4 + (j4 - jd * 3) - 1;
    if ((unsigned)hh < 64u && (unsigned)ww < 64u)
        return q_s[(hh << 6) + ww];
    return 0.0f;
}

__global__ __launch_bounds__(256) void appcomp_kernel(
    const float* __restrict__ key,
    const float* __restrict__ query,
    float* __restrict__ out)
{
    __shared__ float k_s[HW];
    __shared__ float q_s[HW];

    const int bc  = blockIdx.x;          // 2048 blocks, one per (b,c)
    const int tid = threadIdx.x;

    // Phase 1: stage both planes, fully coalesced float4.
    {
        const float4* kg = (const float4*)(key + bc * HW);
        const float4* qg = (const float4*)(query + bc * HW);
        float4* k4 = (float4*)k_s;
        float4* q4 = (float4*)q_s;
        #pragma unroll
        for (int i = 0; i < 4; i++) {
            int idx = i * 256 + tid;
            k4[idx] = kg[idx];
            q4[idx] = qg[idx];
        }
    }
    __syncthreads();

    // Phase 2: 36 chunks of 4 consecutive outputs per thread.
    float* oplane = out + (size_t)bc * 36864;
    #pragma unroll 4
    for (int i = 0; i < 36; i++) {
        int t  = i * 256 + tid;          // chunk id in [0, 9216)
        int r  = t << 2;                 // base p, [0, 36864)
        int j  = t >> 10;                // tap index 0..8 (wave-uniform)
        int l  = r & 4095;
        int h  = l >> 6;
        int w0 = l & 63;                 // multiple of 4

        int jd3 = (j * 11) >> 5;         // j/3
        int dh  = jd3 - 1;
        int dw  = j - jd3 * 3 - 1;       // wave-uniform
        int hh  = h + dh;

        float kf[4];
        if ((unsigned)hh < 64u) {
            const float* rowp = k_s + (hh << 6);
            float4 a = *(const float4*)(rowp + w0);      // 16B-aligned LDS
            if (dw == 0) {
                kf[0] = a.x; kf[1] = a.y; kf[2] = a.z; kf[3] = a.w;
            } else if (dw < 0) {
                kf[0] = (w0 > 0) ? rowp[w0 - 1] : 0.0f;
                kf[1] = a.x; kf[2] = a.y; kf[3] = a.z;
            } else {
                kf[0] = a.y; kf[1] = a.z; kf[2] = a.w;
                kf[3] = (w0 < 60) ? rowp[w0 + 4] : 0.0f;
            }
        } else {
            kf[0] = kf[1] = kf[2] = kf[3] = 0.0f;
        }

        // query factors: 4 consecutive p span at most two l2 = p/9 values
        int l2a   = r / 9;
        int m9    = r - l2a * 9;
        int split = 9 - m9;              // [0, split) use qa, rest qb
        float qa = qload_lds(q_s, l2a);
        float qb = (split < 4) ? qload_lds(q_s, l2a + 1) : 0.0f;

        float f[4];
        #pragma unroll
        for (int q = 0; q < 4; q++)
            f[q] = kf[q] * ((q < split) ? qa : qb);

        *(float4*)(oplane + r) = make_float4(f[0], f[1], f[2], f[3]);
    }
}

extern "C" void kernel_launch(void* const* d_in, const int* in_sizes, int n_in,
                              void* d_out, int out_size, void* d_ws, size_t ws_size,
                              hipStream_t stream) {
    const float* key   = (const float*)d_in[0];
    const float* query = (const float*)d_in[1];
    float* out = (float*)d_out;
    appcomp_kernel<<<2048, 256, 0, stream>>>(key, query, out);
}